// Round 11
// baseline (225.620 us; speedup 1.0000x reference)
//
#include <hip/hip_runtime.h>

#define BB 4
#define NN 16384
#define SS 4096
#define CC 256
#define TLD 132  // gather tile leading dim (words): 128ch + 4 pad, rows 16B-aligned

typedef float f32x4 __attribute__((ext_vector_type(4)));  // for nontemporal builtins

__device__ __forceinline__ bool lexlt(float da, int ia, float db, int ib) {
  // strict (d, idx) lexicographic order — matches jax.lax.top_k tie-break
  return (da < db) || ((da == db) && (ia < ib));
}

// exact np replication: d = qq - 2*dot + kk, left-to-right, no contract
#define DIST3(QX, QY, QZ, QQ, kp) ({                            \
  float _dot = ((QX) * (kp).x + (QY) * (kp).y) + (QZ) * (kp).z; \
  __builtin_fmaf(_dot, -2.0f, (QQ)) + (kp).w;                   \
})

// byte-identical top-3 insert (idempotent when dd >= D2)
#define INS(dd, ss, D0, D1, D2, I0, I1, I2) do {              \
  bool _k2 = (dd) < D2, _k1 = (dd) < D1, _k0 = (dd) < D0;     \
  float _nd2 = __builtin_amdgcn_fmed3f((dd), D1, D2);         \
  float _nd1 = __builtin_amdgcn_fmed3f((dd), D0, D1);         \
  float _nd0 = fminf((dd), D0);                               \
  I2 = _k1 ? I1 : (_k2 ? (ss) : I2);                          \
  I1 = _k0 ? I0 : (_k1 ? (ss) : I1);                          \
  I0 = _k0 ? (ss) : I0;                                       \
  D2 = _nd2; D1 = _nd1; D0 = _nd0;                            \
} while (0)

// ---------------- Kernel A: bundle-gated scan, RQ=2 per lane ----------------
// Grid 1024 = b(4) x seg(4) x nblk(64); 256 thr (4 waves); 4 blocks/CU, 16 waves/CU.
// R11 change vs R10: each lane owns TWO queries (qA = lane, qB = lane+64; 128
// queries/wave), so every wave-uniform ds_read_b128 serves 128 query-dists instead
// of 64 -> per-CU LDS traffic HALVES (the R9/R10 ~82us LDS-pipe floor -> ~41us).
// Wave wv: qg2 = wv&1 (which 128-query group), half = wv>>1 (which 512-cand half).
// Bundle gating as R9/R10: 16-cand branch-free dist block, per-group wave-uniform
// 16-bit masks (tau = d2 frozen per bundle; first bundles tau=inf -> seed), scalar-
// branch insert sweep. Halves merge via the R0/R10-proven 3-step lexlt network.
// Exact: DIST/INSERT bodies byte-identical; s ascending per lane; half0 s-range <
// half1 s-range and the merge prefers the lower index on ties.
__global__ __launch_bounds__(256, 4) void scan_kernel(
    const float* __restrict__ qg, const float* __restrict__ kg,
    float4* __restrict__ dpart, int4* __restrict__ ipart) {
#pragma clang fp contract(off)
  __shared__ __align__(16) float4 kpts[1024];  // 16 KB
  float* md = (float*)kpts;                    // [256][3] floats (3 KB), overlaid
  int* mi = (int*)((char*)kpts + 3072);        // [256][3] ints   (3 KB)

  const int tid = threadIdx.x;
  const int blk = blockIdx.x;
  const int b = blk >> 8;
  const int seg = (blk >> 6) & 3;
  const int n0 = (blk & 63) << 8;  // 256 queries per block
  const int wv = tid >> 6;
  const int lane = tid & 63;
  const int qg2 = wv & 1;   // query group 0/1 (128 queries each)
  const int half = wv >> 1; // candidate half 0/1
  const int qA = n0 + (qg2 << 7) + lane;  // this lane's queries
  const int qB = qA + 64;

  // ---- stage this segment's 1024 points as {x,y,z,kk} ----
  {
    const float* kb = kg + ((long)b * SS + (long)seg * 1024) * 3;
    const float4* src = (const float4*)kb + tid * 3;
    float4 f0 = src[0], f1 = src[1], f2 = src[2];
    float px[4] = {f0.x, f0.w, f1.z, f2.y};
    float py[4] = {f0.y, f1.x, f1.w, f2.z};
    float pz[4] = {f0.z, f1.y, f2.x, f2.w};
#pragma unroll
    for (int m = 0; m < 4; ++m) {
      float kk = (px[m] * px[m] + py[m] * py[m]) + pz[m] * pz[m];  // np order
      kpts[tid * 4 + m] = make_float4(px[m], py[m], pz[m], kk);
    }
  }

  const float* qpA = qg + ((long)b * NN + qA) * 3;
  const float* qpB = qg + ((long)b * NN + qB) * 3;
  float axq = qpA[0], ayq = qpA[1], azq = qpA[2];
  float bxq = qpB[0], byq = qpB[1], bzq = qpB[2];
  float aqq = (axq * axq + ayq * ayq) + azq * azq;  // np sum order
  float bqq = (bxq * bxq + byq * byq) + bzq * bzq;
  float ad0 = 3.4e38f, ad1 = 3.4e38f, ad2 = 3.4e38f;
  float bd0 = 3.4e38f, bd1 = 3.4e38f, bd2 = 3.4e38f;
  int ai0 = 0, ai1 = 0, ai2 = 0;
  int bi0 = 0, bi1 = 0, bi2 = 0;
  __syncthreads();

  const int sb = seg * 1024;
  const int cbase = half << 9;  // this wave's 512-candidate window

  // ---- 32 bundles of 16; tau frozen per bundle (first bundles tau=inf -> seed) ----
  for (int bdl = 0; bdl < 32; ++bdl) {
    const int base = cbase + (bdl << 4);
    const float tauA = ad2;  // per-lane; d2_run <= tau within the bundle
    const float tauB = bd2;
    float dvA[16], dvB[16];
    unsigned mskA = 0, mskB = 0;
#pragma unroll
    for (int sj = 0; sj < 4; ++sj) {  // 4 cands per sub-bundle bounds VGPR pressure
      float4 ka = kpts[base + 4 * sj + 0];
      float4 kb_ = kpts[base + 4 * sj + 1];
      float4 kc = kpts[base + 4 * sj + 2];
      float4 kd = kpts[base + 4 * sj + 3];
      dvA[4 * sj + 0] = DIST3(axq, ayq, azq, aqq, ka);
      dvB[4 * sj + 0] = DIST3(bxq, byq, bzq, bqq, ka);
      dvA[4 * sj + 1] = DIST3(axq, ayq, azq, aqq, kb_);
      dvB[4 * sj + 1] = DIST3(bxq, byq, bzq, bqq, kb_);
      dvA[4 * sj + 2] = DIST3(axq, ayq, azq, aqq, kc);
      dvB[4 * sj + 2] = DIST3(bxq, byq, bzq, bqq, kc);
      dvA[4 * sj + 3] = DIST3(axq, ayq, azq, aqq, kd);
      dvB[4 * sj + 3] = DIST3(bxq, byq, bzq, bqq, kd);
    }
#pragma unroll
    for (int j = 0; j < 16; ++j) {
      mskA |= (__any(dvA[j] < tauA) ? 1u : 0u) << j;
      mskB |= (__any(dvB[j] < tauB) ? 1u : 0u) << j;
    }
    if (mskA) {
#pragma unroll
      for (int j = 0; j < 16; ++j) {
        if (mskA & (1u << j)) INS(dvA[j], sb + base + j, ad0, ad1, ad2, ai0, ai1, ai2);
      }
    }
    if (mskB) {
#pragma unroll
      for (int j = 0; j < 16; ++j) {
        if (mskB & (1u << j)) INS(dvB[j], sb + base + j, bd0, bd1, bd2, bi0, bi1, bi2);
      }
    }
  }

  // ---- intra-block merge of the two half-seg waves (R0/R10-proven network) ----
  __syncthreads();  // all kpts reads done; md/mi overlay kpts
  if (half == 1) {
    int baseA = ((qg2 << 7) + lane) * 3;
    int baseB = baseA + 64 * 3;
    md[baseA + 0] = ad0; md[baseA + 1] = ad1; md[baseA + 2] = ad2;
    mi[baseA + 0] = ai0; mi[baseA + 1] = ai1; mi[baseA + 2] = ai2;
    md[baseB + 0] = bd0; md[baseB + 1] = bd1; md[baseB + 2] = bd2;
    mi[baseB + 0] = bi0; mi[baseB + 1] = bi1; mi[baseB + 2] = bi2;
  }
  __syncthreads();
  if (half == 0) {
#pragma unroll
    for (int p = 0; p < 2; ++p) {
      int qi = (qg2 << 7) + (p ? lane + 64 : lane);
      int basei = qi * 3;
      float A0 = p ? bd0 : ad0, A1 = p ? bd1 : ad1, A2 = p ? bd2 : ad2;
      int B0 = p ? bi0 : ai0, B1 = p ? bi1 : ai1, B2 = p ? bi2 : ai2;
      float E0 = md[basei + 0], E1 = md[basei + 1], E2 = md[basei + 2];
      int F0 = mi[basei + 0], F1 = mi[basei + 1], F2 = mi[basei + 2];
      bool t = lexlt(E0, F0, A0, B0);
      float r0 = t ? E0 : A0; int s0 = t ? F0 : B0;
      float nA0 = t ? A0 : A1, nA1 = t ? A1 : A2;
      int nB0 = t ? B0 : B1, nB1 = t ? B1 : B2;
      float nE0 = t ? E1 : E0, nE1 = t ? E2 : E1;
      int nF0 = t ? F1 : F0, nF1 = t ? F2 : F1;
      bool u = lexlt(nE0, nF0, nA0, nB0);
      float r1 = u ? nE0 : nA0; int s1 = u ? nF0 : nB0;
      float mA0 = u ? nA0 : nA1; int mB0 = u ? nB0 : nB1;
      float mE0 = u ? nE1 : nE0; int mF0 = u ? nF1 : nF0;
      bool w = lexlt(mE0, mF0, mA0, mB0);
      float r2 = w ? mE0 : mA0; int s2 = w ? mF0 : mB0;
      long gid = (long)b * NN + n0 + qi;
      dpart[gid * 4 + seg] = make_float4(r0, r1, r2, 0.0f);
      ipart[gid * 4 + seg] = make_int4(s0, s1, s2, 0);
    }
  }
}

// ---------------- Kernel B: merge partials + gather + transpose ----------------
// Verbatim R3 (v3b): XCD-affinity decomposition, measured ~21 us. Grid 2048;
// round-robin dispatch -> XCD = bid&7; each XCD owns one (batch, channel-half):
// per-XCD V working set 2 MB < 4 MB L2. NT stores keep writes from evicting V.
__global__ __launch_bounds__(256, 4) void gather_kernel(
    const float* __restrict__ vg, const float4* __restrict__ dpart,
    const int4* __restrict__ ipart, float* __restrict__ outg) {
#pragma clang fp contract(off)
  __shared__ __align__(16) float tile[64 * TLD];  // 33.8 KB
  __shared__ float sw[64][3];
  __shared__ int si[64][3];

  const int tid = threadIdx.x;
  const int bid = blockIdx.x;
  const int xcd = bid & 7;     // dispatch round-robin: block -> XCD
  const int b = xcd >> 1;      // 2 XCDs per batch
  const int chunk = xcd & 1;   // which 128-channel half this XCD handles
  const int nblk = bid >> 3;   // 0..255
  const int n0 = nblk << 6;    // 64 queries per block

  if (tid < 64) {
    long gid = (long)b * NN + n0 + tid;
    float D0 = 3.4e38f, D1 = 3.4e38f, D2 = 3.4e38f;
    int I0 = -1, I1 = -1, I2 = -1;
#pragma unroll
    for (int seg = 0; seg < 4; ++seg) {
      float4 dv = dpart[gid * 4 + seg];
      int4 iv = ipart[gid * 4 + seg];
      float ds_[3] = {dv.x, dv.y, dv.z};
      int is_[3] = {iv.x, iv.y, iv.z};
      for (int r = 0; r < 3; ++r) {
        float d = ds_[r];
        int s = is_[r];
        if (lexlt(d, s, D2, I2)) {
          if (lexlt(d, s, D1, I1)) {
            D2 = D1; I2 = I1;
            if (lexlt(d, s, D0, I0)) { D1 = D0; I1 = I0; D0 = d; I0 = s; }
            else { D1 = d; I1 = s; }
          } else { D2 = d; I2 = s; }
        }
      }
    }
    // weights exactly as ref: recip = 1/(d+1e-8) on ascending dists, then normalize
    float r0 = 1.0f / (D0 + 1e-8f);
    float r1 = 1.0f / (D1 + 1e-8f);
    float r2 = 1.0f / (D2 + 1e-8f);
    float rs = (r0 + r1) + r2;
    sw[tid][0] = r0 / rs; sw[tid][1] = r1 / rs; sw[tid][2] = r2 / rs;
    si[tid][0] = I0; si[tid][1] = I1; si[tid][2] = I2;
  }
  __syncthreads();

  const int wv = tid >> 6;      // wave id 0..3 -> owns queries wv*16 .. wv*16+15
  const int lane = tid & 63;
  const int qh = lane >> 5;     // half-wave: which of 2 queries this iteration
  const int slot = lane & 31;   // f4 slot within the 128-channel half
  const float* vb = vg + (long)b * SS * CC + chunk * 128;

#pragma unroll 4
  for (int it = 0; it < 8; ++it) {
    int qs = wv * 16 + it * 2 + qh;
    float w0 = sw[qs][0], w1 = sw[qs][1], w2 = sw[qs][2];
    const float4* r0p = (const float4*)(vb + (long)si[qs][0] * CC);
    const float4* r1p = (const float4*)(vb + (long)si[qs][1] * CC);
    const float4* r2p = (const float4*)(vb + (long)si[qs][2] * CC);
    float4 a0 = r0p[slot], a1 = r1p[slot], a2 = r2p[slot];
    float4 acc;
    acc.x = (w0 * a0.x + w1 * a1.x) + w2 * a2.x;
    acc.y = (w0 * a0.y + w1 * a1.y) + w2 * a2.y;
    acc.z = (w0 * a0.z + w1 * a1.z) + w2 * a2.z;
    acc.w = (w0 * a0.w + w1 * a1.w) + w2 * a2.w;
    *(float4*)&tile[qs * TLD + slot * 4] = acc;
  }
  __syncthreads();

  // store: 128 channels x 64 n; each thread assembles float4 along n (non-temporal)
  {
    const int nf = tid & 15;   // f4 group along n
    const int cb0 = tid >> 4;  // channel base 0..15
    const int q0 = nf << 2;    // first of 4 consecutive queries (n)
#pragma unroll 2
    for (int it = 0; it < 8; ++it) {
      int cl = cb0 + it * 16;           // channel within half 0..127
      int cch = (chunk << 7) + cl;      // global channel
      f32x4 val;
      val.x = tile[(q0 + 0) * TLD + cl];
      val.y = tile[(q0 + 1) * TLD + cl];
      val.z = tile[(q0 + 2) * TLD + cl];
      val.w = tile[(q0 + 3) * TLD + cl];
      __builtin_nontemporal_store(
          val, (f32x4*)&outg[((long)(b * CC + cch)) * NN + n0 + q0]);
    }
  }
}

extern "C" void kernel_launch(void* const* d_in, const int* in_sizes, int n_in,
                              void* d_out, int out_size, void* d_ws, size_t ws_size,
                              hipStream_t stream) {
  const float* q = (const float*)d_in[0];
  const float* k = (const float*)d_in[1];
  const float* v = (const float*)d_in[2];
  float* out = (float*)d_out;
  float4* dpart = (float4*)d_ws;                                          // 4 MB
  int4* ipart = (int4*)((char*)d_ws + (size_t)BB * NN * 4 * 16);          // 4 MB
  hipLaunchKernelGGL(scan_kernel, dim3(1024), dim3(256), 0, stream, q, k, dpart, ipart);
  hipLaunchKernelGGL(gather_kernel, dim3(2048), dim3(256), 0, stream, v, dpart, ipart, out);
}

// Round 12
// 213.215 us; speedup vs baseline: 1.0582x; 1.0582x over previous
//
#include <hip/hip_runtime.h>

#define BB 4
#define NN 16384
#define SS 4096
#define CC 256
#define TLD 132  // gather tile leading dim (words): 128ch + 4 pad, rows 16B-aligned

typedef float f32x4 __attribute__((ext_vector_type(4)));  // for nontemporal builtins

__device__ __forceinline__ bool lexlt(float da, int ia, float db, int ib) {
  // strict (d, idx) lexicographic order — matches jax.lax.top_k tie-break
  return (da < db) || ((da == db) && (ia < ib));
}

// exact np replication: d = qq - 2*dot + kk, left-to-right, no contract
#define DIST(kp) ({                                        \
  float _dot = (qx * (kp).x + qy * (kp).y) + qz * (kp).z;  \
  __builtin_fmaf(_dot, -2.0f, qq) + (kp).w;                \
})

// byte-identical top-3 insert (idempotent when dd >= d2)
#define INSERT(dd, ss) do {                                \
  bool _k2 = (dd) < d2, _k1 = (dd) < d1, _k0 = (dd) < d0;  \
  float _nd2 = __builtin_amdgcn_fmed3f((dd), d1, d2);      \
  float _nd1 = __builtin_amdgcn_fmed3f((dd), d0, d1);      \
  float _nd0 = fminf((dd), d0);                            \
  i2 = _k1 ? i1 : (_k2 ? (ss) : i2);                       \
  i1 = _k0 ? i0 : (_k1 ? (ss) : i1);                       \
  i0 = _k0 ? (ss) : i0;                                    \
  d2 = _nd2; d1 = _nd1; d0 = _nd0;                         \
} while (0)

// ---------------- Kernel A: bundle-gated top-3 scan, lane = query ----------------
// R9 configuration — the measured optimum (122.5 us scan, 207.8 us total).
// Grid 1024 = b(4) x seg(4) x qgrp(64); 256 thr (4 waves); 4 blocks/CU, 16 waves/CU.
// Each wave owns 64 queries over 1024 staged cands. Gate is BUNDLED per 16
// candidates: branch-free dist block (16 ds_read_b128 + 112 FLOPs, pipelines like
// the R0 straight-line loop); a 16-bit wave-uniform mask (bit j = __any(dv[j]<tau),
// tau = d2 frozen at bundle start) drives a scalar-branch insert sweep with
// compile-time dv[] indices. Gate exact: needed insert has d < d2_run <= tau ->
// bit set; insert body idempotent & byte-identical; s ascending per lane.
// Diagnostic arc R9-R11 (2x occupancy: +-0; half LDS: +14us) shows this point is
// VALU-issue-bound at throttled clock, ~90% of the 8-op/pair exactness floor.
__global__ __launch_bounds__(256, 4) void scan_kernel(
    const float* __restrict__ qg, const float* __restrict__ kg,
    float4* __restrict__ dpart, int4* __restrict__ ipart) {
#pragma clang fp contract(off)
  __shared__ __align__(16) float4 kpts[1024];  // 16 KB

  const int tid = threadIdx.x;
  const int blk = blockIdx.x;
  const int b = blk >> 8;
  const int seg = (blk >> 6) & 3;
  const int n0 = (blk & 63) << 8;  // 256 queries per block
  const int wv = tid >> 6;
  const int lane = tid & 63;
  const int q = n0 + wv * 64 + lane;  // this lane's query

  // ---- stage this segment's 1024 points as {x,y,z,kk} ----
  {
    const float* kb = kg + ((long)b * SS + (long)seg * 1024) * 3;
    const float4* src = (const float4*)kb + tid * 3;
    float4 f0 = src[0], f1 = src[1], f2 = src[2];
    float px[4] = {f0.x, f0.w, f1.z, f2.y};
    float py[4] = {f0.y, f1.x, f1.w, f2.z};
    float pz[4] = {f0.z, f1.y, f2.x, f2.w};
#pragma unroll
    for (int m = 0; m < 4; ++m) {
      float kk = (px[m] * px[m] + py[m] * py[m]) + pz[m] * pz[m];  // np order
      kpts[tid * 4 + m] = make_float4(px[m], py[m], pz[m], kk);
    }
  }

  const float* qp = qg + ((long)b * NN + q) * 3;
  float qx = qp[0], qy = qp[1], qz = qp[2];
  float qq = (qx * qx + qy * qy) + qz * qz;  // np sum order
  float d0 = 3.4e38f, d1 = 3.4e38f, d2 = 3.4e38f;
  int i0 = 0, i1 = 0, i2 = 0;
  __syncthreads();

  const int sb = seg * 1024;

  // ---- prefix: 16 bundles of 16, ungated (seeds the top-3) ----
  for (int bdl = 0; bdl < 16; ++bdl) {
    const int base = bdl << 4;
    float dv[16];
#pragma unroll
    for (int sj = 0; sj < 4; ++sj) {  // 4 cands per sub-bundle bounds VGPR pressure
      float4 ka = kpts[base + 4 * sj + 0];
      float4 kb_ = kpts[base + 4 * sj + 1];
      float4 kc = kpts[base + 4 * sj + 2];
      float4 kd = kpts[base + 4 * sj + 3];
      dv[4 * sj + 0] = DIST(ka);
      dv[4 * sj + 1] = DIST(kb_);
      dv[4 * sj + 2] = DIST(kc);
      dv[4 * sj + 3] = DIST(kd);
    }
#pragma unroll
    for (int j = 0; j < 16; ++j) INSERT(dv[j], sb + base + j);
  }

  // ---- gated: 48 bundles of 16, tau frozen per bundle ----
  for (int bdl = 16; bdl < 64; ++bdl) {
    const int base = bdl << 4;
    const float tau = d2;  // per-lane; d2_run <= tau within the bundle
    float dv[16];
    unsigned msk = 0;
#pragma unroll
    for (int sj = 0; sj < 4; ++sj) {
      float4 ka = kpts[base + 4 * sj + 0];
      float4 kb_ = kpts[base + 4 * sj + 1];
      float4 kc = kpts[base + 4 * sj + 2];
      float4 kd = kpts[base + 4 * sj + 3];
      dv[4 * sj + 0] = DIST(ka);
      dv[4 * sj + 1] = DIST(kb_);
      dv[4 * sj + 2] = DIST(kc);
      dv[4 * sj + 3] = DIST(kd);
    }
#pragma unroll
    for (int j = 0; j < 16; ++j) msk |= (__any(dv[j] < tau) ? 1u : 0u) << j;
    if (msk) {
#pragma unroll
      for (int j = 0; j < 16; ++j) {
        if (msk & (1u << j)) INSERT(dv[j], sb + base + j);
      }
    }
  }

  // ---- write this lane's partial (no intra-block merge needed) ----
  long gid = (long)b * NN + q;
  dpart[gid * 4 + seg] = make_float4(d0, d1, d2, 0.0f);
  ipart[gid * 4 + seg] = make_int4(i0, i1, i2, 0);
}

// ---------------- Kernel B: merge partials + gather + transpose ----------------
// Verbatim R3 (v3b): XCD-affinity decomposition, measured ~21 us. Grid 2048;
// round-robin dispatch -> XCD = bid&7; each XCD owns one (batch, channel-half):
// per-XCD V working set 2 MB < 4 MB L2. NT stores keep writes from evicting V.
__global__ __launch_bounds__(256, 4) void gather_kernel(
    const float* __restrict__ vg, const float4* __restrict__ dpart,
    const int4* __restrict__ ipart, float* __restrict__ outg) {
#pragma clang fp contract(off)
  __shared__ __align__(16) float tile[64 * TLD];  // 33.8 KB
  __shared__ float sw[64][3];
  __shared__ int si[64][3];

  const int tid = threadIdx.x;
  const int bid = blockIdx.x;
  const int xcd = bid & 7;     // dispatch round-robin: block -> XCD
  const int b = xcd >> 1;      // 2 XCDs per batch
  const int chunk = xcd & 1;   // which 128-channel half this XCD handles
  const int nblk = bid >> 3;   // 0..255
  const int n0 = nblk << 6;    // 64 queries per block

  if (tid < 64) {
    long gid = (long)b * NN + n0 + tid;
    float D0 = 3.4e38f, D1 = 3.4e38f, D2 = 3.4e38f;
    int I0 = -1, I1 = -1, I2 = -1;
#pragma unroll
    for (int seg = 0; seg < 4; ++seg) {
      float4 dv = dpart[gid * 4 + seg];
      int4 iv = ipart[gid * 4 + seg];
      float ds_[3] = {dv.x, dv.y, dv.z};
      int is_[3] = {iv.x, iv.y, iv.z};
      for (int r = 0; r < 3; ++r) {
        float d = ds_[r];
        int s = is_[r];
        if (lexlt(d, s, D2, I2)) {
          if (lexlt(d, s, D1, I1)) {
            D2 = D1; I2 = I1;
            if (lexlt(d, s, D0, I0)) { D1 = D0; I1 = I0; D0 = d; I0 = s; }
            else { D1 = d; I1 = s; }
          } else { D2 = d; I2 = s; }
        }
      }
    }
    // weights exactly as ref: recip = 1/(d+1e-8) on ascending dists, then normalize
    float r0 = 1.0f / (D0 + 1e-8f);
    float r1 = 1.0f / (D1 + 1e-8f);
    float r2 = 1.0f / (D2 + 1e-8f);
    float rs = (r0 + r1) + r2;
    sw[tid][0] = r0 / rs; sw[tid][1] = r1 / rs; sw[tid][2] = r2 / rs;
    si[tid][0] = I0; si[tid][1] = I1; si[tid][2] = I2;
  }
  __syncthreads();

  const int wv = tid >> 6;      // wave id 0..3 -> owns queries wv*16 .. wv*16+15
  const int lane = tid & 63;
  const int qh = lane >> 5;     // half-wave: which of 2 queries this iteration
  const int slot = lane & 31;   // f4 slot within the 128-channel half
  const float* vb = vg + (long)b * SS * CC + chunk * 128;

#pragma unroll 4
  for (int it = 0; it < 8; ++it) {
    int qs = wv * 16 + it * 2 + qh;
    float w0 = sw[qs][0], w1 = sw[qs][1], w2 = sw[qs][2];
    const float4* r0p = (const float4*)(vb + (long)si[qs][0] * CC);
    const float4* r1p = (const float4*)(vb + (long)si[qs][1] * CC);
    const float4* r2p = (const float4*)(vb + (long)si[qs][2] * CC);
    float4 a0 = r0p[slot], a1 = r1p[slot], a2 = r2p[slot];
    float4 acc;
    acc.x = (w0 * a0.x + w1 * a1.x) + w2 * a2.x;
    acc.y = (w0 * a0.y + w1 * a1.y) + w2 * a2.y;
    acc.z = (w0 * a0.z + w1 * a1.z) + w2 * a2.z;
    acc.w = (w0 * a0.w + w1 * a1.w) + w2 * a2.w;
    *(float4*)&tile[qs * TLD + slot * 4] = acc;
  }
  __syncthreads();

  // store: 128 channels x 64 n; each thread assembles float4 along n (non-temporal)
  {
    const int nf = tid & 15;   // f4 group along n
    const int cb0 = tid >> 4;  // channel base 0..15
    const int q0 = nf << 2;    // first of 4 consecutive queries (n)
#pragma unroll 2
    for (int it = 0; it < 8; ++it) {
      int cl = cb0 + it * 16;           // channel within half 0..127
      int cch = (chunk << 7) + cl;      // global channel
      f32x4 val;
      val.x = tile[(q0 + 0) * TLD + cl];
      val.y = tile[(q0 + 1) * TLD + cl];
      val.z = tile[(q0 + 2) * TLD + cl];
      val.w = tile[(q0 + 3) * TLD + cl];
      __builtin_nontemporal_store(
          val, (f32x4*)&outg[((long)(b * CC + cch)) * NN + n0 + q0]);
    }
  }
}

extern "C" void kernel_launch(void* const* d_in, const int* in_sizes, int n_in,
                              void* d_out, int out_size, void* d_ws, size_t ws_size,
                              hipStream_t stream) {
  const float* q = (const float*)d_in[0];
  const float* k = (const float*)d_in[1];
  const float* v = (const float*)d_in[2];
  float* out = (float*)d_out;
  float4* dpart = (float4*)d_ws;                                          // 4 MB
  int4* ipart = (int4*)((char*)d_ws + (size_t)BB * NN * 4 * 16);          // 4 MB
  hipLaunchKernelGGL(scan_kernel, dim3(1024), dim3(256), 0, stream, q, k, dpart, ipart);
  hipLaunchKernelGGL(gather_kernel, dim3(2048), dim3(256), 0, stream, v, dpart, ipart, out);
}